// Round 18
// baseline (82.487 us; speedup 1.0000x reference)
//
#include <hip/hip_runtime.h>
#include <hip/hip_bf16.h>

typedef unsigned short u16;
typedef u16 u16x4 __attribute__((ext_vector_type(4)));
typedef u16 u16x8 __attribute__((ext_vector_type(8)));
typedef __bf16 bf16x8 __attribute__((ext_vector_type(8)));
typedef float f32x4 __attribute__((ext_vector_type(4)));

static __device__ __forceinline__ u16 f2bf(float f) {
  return __builtin_bit_cast(u16, __float2bfloat16(f));   // RTNE; pairs into v_cvt_pk_bf16_f32
}

// async global->LDS, 16B per lane. LDS dest = wave-uniform base + lane*16.
static __device__ __forceinline__ void gload16(const u16* g, u16* l) {
  __builtin_amdgcn_global_load_lds(
      (const __attribute__((address_space(1))) unsigned*)g,
      (__attribute__((address_space(3))) unsigned*)l, 16, 0, 0);
}

// Barriers guarding LDS buffer handoff MUST drain lgkmcnt inside the asm
// (rule #18: hipcc can sink register-only MFMAs below an asm s_barrier,
// leaving their feeding ds_reads outstanding across the barrier).
#define WAIT8_BAR() asm volatile("s_waitcnt vmcnt(8) lgkmcnt(0)\ns_barrier" ::: "memory")
#define WAIT0_BAR() asm volatile("s_waitcnt vmcnt(0) lgkmcnt(0)\ns_barrier" ::: "memory")
#define BAR()       asm volatile("s_waitcnt lgkmcnt(0)\ns_barrier" ::: "memory")

// ---------------- fused cvt: x f32->bf16 (blocks 0..3071) ----------------
//                  W [768][2304] f32 -> WbT [2304][768] bf16 (blocks 3072..4799)
__global__ __launch_bounds__(256) void cvt_all_kernel(const float* __restrict__ xin,
                                                      u16* __restrict__ xout,
                                                      const float* __restrict__ W,
                                                      u16* __restrict__ WT) {
  int bid = blockIdx.x;
  if (bid < 3072) {
    int i = bid * 256 + threadIdx.x;               // 8 elems per thread
    const float4* p = reinterpret_cast<const float4*>(xin) + (size_t)i * 2;
    float4 a = p[0], b = p[1];
    u16x8 o;
    o[0] = f2bf(a.x); o[1] = f2bf(a.y); o[2] = f2bf(a.z); o[3] = f2bf(a.w);
    o[4] = f2bf(b.x); o[5] = f2bf(b.y); o[6] = f2bf(b.z); o[7] = f2bf(b.w);
    reinterpret_cast<u16x8*>(xout)[i] = o;
  } else {
    int id = bid - 3072;                           // 0..1727
    int n  = (id % 9) * 256 + threadIdx.x;         // 0..2303
    int k0 = (id / 9) * 4;                         // 0..764
    u16x4 o;
#pragma unroll
    for (int j = 0; j < 4; ++j) o[j] = f2bf(W[(size_t)(k0 + j) * 2304 + n]);
    *reinterpret_cast<u16x4*>(WT + (size_t)n * 768 + k0) = o;
  }
}

// ---------------- QKV GEMM: [8192x768] @ [768x2304] + bias ----------------
// 128x128 tile, BK=64, both-sides XOR swizzle, THREE-buffer rotation:
// per phase: WAIT8_BAR -> STAGE(kt+2) -> compute(kt). One barrier per phase
// (was two), stage lead = 2 tile-computes (~1600cy >= HBM latency). 96KB LDS
// -> 1 block/CU, grid 1152 = 4.5 uniform rounds. Identity block map.
// LDS-transpose epilogue (stride 72 -> 16B-aligned readback), coalesced q/k.
// q pre-scaled by 0.125. writes q[bh][t][d], k[bh][t][d], vT[bh][d][t].

static __device__ __forceinline__ void gemm_compute64(
    const u16* __restrict__ as, const u16* __restrict__ bs,
    int wm, int wn, int l16, int g, f32x4 (&acc)[4][4]) {
  bf16x8 af[4][2], bfr[4][2];
#pragma unroll
  for (int mi = 0; mi < 4; ++mi)
#pragma unroll
    for (int ks = 0; ks < 2; ++ks)
      af[mi][ks] = __builtin_bit_cast(bf16x8,
          *reinterpret_cast<const u16x8*>(
              as + (wm + mi * 16 + l16) * 64 + (((ks * 4 + g) ^ (l16 & 7)) * 8)));
#pragma unroll
  for (int ni = 0; ni < 4; ++ni)
#pragma unroll
    for (int ks = 0; ks < 2; ++ks)
      bfr[ni][ks] = __builtin_bit_cast(bf16x8,
          *reinterpret_cast<const u16x8*>(
              bs + (wn + ni * 16 + l16) * 64 + (((ks * 4 + g) ^ (l16 & 7)) * 8)));
#pragma unroll
  for (int ks = 0; ks < 2; ++ks)
#pragma unroll
    for (int mi = 0; mi < 4; ++mi)
#pragma unroll
      for (int ni = 0; ni < 4; ++ni)
        acc[mi][ni] = __builtin_amdgcn_mfma_f32_16x16x32_bf16(
            af[mi][ks], bfr[ni][ks], acc[mi][ni], 0, 0, 0);
}

__global__ __launch_bounds__(256, 1) void gemm_qkv_kernel(
    const u16* __restrict__ A, const u16* __restrict__ Bt,
    const float* __restrict__ bias,
    u16* __restrict__ qb, u16* __restrict__ kb, u16* __restrict__ vTb) {
  // 96KB: A bufs 0..2 (16KB each) | B bufs 0..2 (16KB each)
  __shared__ __align__(16) u16 smem[49152];
  u16* ab0 = smem;
  u16* ab1 = smem + 8192;
  u16* ab2 = smem + 16384;
  u16* bb0 = smem + 24576;
  u16* bb1 = smem + 32768;
  u16* bb2 = smem + 40960;
  const int K = 768;
  int tid = threadIdx.x;
  int lane = tid & 63;
  int wave = tid >> 6;

  int m0 = blockIdx.x * 128;       // gridDim.x = 64 (identity map: m%8==XCD)
  int n0 = blockIdx.y * 128;       // gridDim.y = 18

  int wm = (wave >> 1) * 64;
  int wn = (wave & 1) * 64;
  int l16 = lane & 15, g = lane >> 4;

  int r8 = lane >> 3;
  int cs = (lane & 7) ^ (r8 & 7);
  const u16* gA = A  + (size_t)(m0 + wave * 32 + r8) * K + cs * 8;
  const u16* gB = Bt + (size_t)(n0 + wave * 32 + r8) * K + cs * 8;
  int lofs = wave * 2048;

  f32x4 acc[4][4];
#pragma unroll
  for (int mi = 0; mi < 4; ++mi)
#pragma unroll
    for (int ni = 0; ni < 4; ++ni) acc[mi][ni] = (f32x4){0.f, 0.f, 0.f, 0.f};

#define STAGE(Abuf, Bbuf, kk)                              \
  do {                                                     \
    gload16(gA + (kk),           Abuf + lofs);             \
    gload16(gA + (kk) +  8 * K,  Abuf + lofs + 512);       \
    gload16(gA + (kk) + 16 * K,  Abuf + lofs + 1024);      \
    gload16(gA + (kk) + 24 * K,  Abuf + lofs + 1536);      \
    gload16(gB + (kk),           Bbuf + lofs);             \
    gload16(gB + (kk) +  8 * K,  Bbuf + lofs + 512);       \
    gload16(gB + (kk) + 16 * K,  Bbuf + lofs + 1024);      \
    gload16(gB + (kk) + 24 * K,  Bbuf + lofs + 1536);      \
  } while (0)

  // prologue: tiles 0,1 in flight (16 loads)
  STAGE(ab0, bb0, 0);
  STAGE(ab1, bb1, 64);
  // phases kt=0..8 (3 groups of 3): WAIT(kt landed) -> STAGE(kt+2) -> compute(kt)
  // Race-freedom: STAGE at kt targets buf[(kt+2)%3], last read at phase kt-1,
  // whose reads are drained by this phase's barrier (lgkmcnt(0) inside).
  for (int j = 0; j < 3; ++j) {
    int kb = j * 192;
    WAIT8_BAR(); STAGE(ab2, bb2, kb + 128); gemm_compute64(ab0, bb0, wm, wn, l16, g, acc);
    WAIT8_BAR(); STAGE(ab0, bb0, kb + 192); gemm_compute64(ab1, bb1, wm, wn, l16, g, acc);
    WAIT8_BAR(); STAGE(ab1, bb1, kb + 256); gemm_compute64(ab2, bb2, wm, wn, l16, g, acc);
  }
  // tail: kt=9 (stage tile 11), 10, 11
  WAIT8_BAR(); STAGE(ab2, bb2, 704); gemm_compute64(ab0, bb0, wm, wn, l16, g, acc);
  WAIT8_BAR();                       gemm_compute64(ab1, bb1, wm, wn, l16, g, acc);
  WAIT0_BAR();                       gemm_compute64(ab2, bb2, wm, wn, l16, g, acc);
#undef STAGE

  BAR();   // all LDS reads drained -> smem reusable as epilogue scratch

  // epilogue. wave tile = 64 t-rows x 64 n-cols, one region & one head each.
  int tbase = m0 & 1023;
  int b = m0 >> 10;
  int nbase = n0 + wn;
  int region = nbase / 768;
  int c0 = nbase - region * 768;
  int h = c0 >> 6;
  int bh = b * 12 + h;
  int tb0 = tbase + wm;
  float scl = (region == 0) ? 0.125f : 1.0f;
  float bvs[4];
#pragma unroll
  for (int ni = 0; ni < 4; ++ni) bvs[ni] = bias[nbase + ni * 16 + l16] * scl;

  if (region == 2) {
    // vT[bh][d][t]: b64 stores along t
    int d0 = c0 & 63;
    int g4 = g * 4;
#pragma unroll
    for (int ni = 0; ni < 4; ++ni) {
      int d = d0 + ni * 16 + l16;
#pragma unroll
      for (int mi = 0; mi < 4; ++mi) {
        int t0 = tb0 + mi * 16 + g4;
        u16x4 pv;
#pragma unroll
        for (int r = 0; r < 4; ++r) pv[r] = f2bf(acc[mi][ni][r] + bvs[ni]);
        *reinterpret_cast<u16x4*>(vTb + ((size_t)bh * 64 + d) * 1024 + t0) = pv;
      }
    }
  } else {
    // q/k[bh][t][d]: transpose via per-wave LDS scratch (stride 72 -> 144B
    // rows, 16B-aligned readback), then 8 coalesced dwordx4 stores.
    u16* scr = smem + wave * (64 * 72);
    u16* dst = (region == 0) ? qb : kb;
#pragma unroll
    for (int ni = 0; ni < 4; ++ni)
#pragma unroll
      for (int mi = 0; mi < 4; ++mi)
#pragma unroll
        for (int r = 0; r < 4; ++r)
          scr[(mi * 16 + g * 4 + r) * 72 + ni * 16 + l16] =
              f2bf(fmaf(acc[mi][ni][r], scl, bvs[ni]));
    int rr = lane >> 3, cc = lane & 7;
#pragma unroll
    for (int i = 0; i < 8; ++i) {
      u16x8 v = *reinterpret_cast<const u16x8*>(scr + (i * 8 + rr) * 72 + cc * 8);
      *reinterpret_cast<u16x8*>(
          dst + ((size_t)bh * 1024 + tb0 + i * 8 + rr) * 64 + cc * 8) = v;
    }
  }
}

// ---------------- causal relu attention (block-shared K/V staging) ----------------
// y[b,h,q,:] = sum_{k<=q} relu(q.k) * v[k]   (scale pre-folded into q)
// Block = 4 waves, same head, q-groups qbase+{0,32,64,96}. K/V 64-key tiles
// staged once per block into double-buffered LDS via global_load_lds, XOR-chunk
// swizzle (both-sides). One vmcnt(0)+lgkmcnt(0)+barrier per tile.
__global__ __launch_bounds__(256, 3) void attn_kernel(
    const u16* __restrict__ qb, const u16* __restrict__ kb,
    const u16* __restrict__ vTb, float* __restrict__ out) {
  __shared__ __align__(16) u16 kbuf0[64 * 64], kbuf1[64 * 64];
  __shared__ __align__(16) u16 vbuf0[64 * 64], vbuf1[64 * 64];
  __shared__ __align__(16) u16 plds[4][32 * 72];
  int lane = threadIdx.x & 63;
  int wave = threadIdx.x >> 6;
  int bh = blockIdx.x;                           // 0..95
  int qbase = (7 - blockIdx.y) * 128;            // heaviest blocks first
  int q0 = qbase + wave * 32;
  int b = bh / 12, h = bh - b * 12;
  const u16* Q  = qb  + (size_t)bh * 65536;
  const u16* Kp = kb  + (size_t)bh * 65536;
  const u16* Vt = vTb + (size_t)bh * 65536;
  int l16 = lane & 15, g = lane >> 4;
  u16* pw = &plds[wave][0];

  int ntw = (q0 >> 6) + 1;        // this wave's active tiles
  int ntB = (qbase >> 6) + 2;     // block-uniform loop bound
  int qoff = q0 & 63;             // 0 or 32

  int r8q = lane >> 3;
  int csw = (lane & 7) ^ (r8q & 7);
  const u16* kSrc = Kp + (size_t)(wave * 16 + r8q) * 64 + csw * 8;
  const u16* vSrc = Vt + (size_t)(wave * 16 + r8q) * 1024 + csw * 8;
  int sofs = wave * 1024;

#define ASTAGE(kbuf, vbuf, kbase)                                   \
  do {                                                              \
    gload16(kSrc + (size_t)(kbase) * 64,       kbuf + sofs);        \
    gload16(kSrc + (size_t)((kbase) + 8) * 64, kbuf + sofs + 512);  \
    gload16(vSrc + (kbase),                    vbuf + sofs);        \
    gload16(vSrc + (kbase) + 8 * 1024,         vbuf + sofs + 512);  \
  } while (0)

  bf16x8 qf[2][2];
#pragma unroll
  for (int qi = 0; qi < 2; ++qi)
#pragma unroll
    for (int ks = 0; ks < 2; ++ks)
      qf[qi][ks] = __builtin_bit_cast(bf16x8,
          *reinterpret_cast<const u16x8*>(Q + (q0 + qi * 16 + l16) * 64 + ks * 32 + g * 8));

  f32x4 y[2][4];
#pragma unroll
  for (int mi = 0; mi < 2; ++mi)
#pragma unroll
    for (int ni = 0; ni < 4; ++ni) y[mi][ni] = (f32x4){0.f, 0.f, 0.f, 0.f};

  ASTAGE(kbuf0, vbuf0, 0);
  WAIT0_BAR();

  for (int kt = 0; kt < ntB; ++kt) {
    u16 *kcur, *vcur, *knx, *vnx;
    if (kt & 1) { kcur = kbuf1; vcur = vbuf1; knx = kbuf0; vnx = vbuf0; }
    else        { kcur = kbuf0; vcur = vbuf0; knx = kbuf1; vnx = vbuf1; }

    if (kt + 1 < ntB) ASTAGE(knx, vnx, (kt + 1) << 6);

    if (kt < ntw) {
      bf16x8 kf[4][2];
#pragma unroll
      for (int kj = 0; kj < 4; ++kj)
#pragma unroll
        for (int ks = 0; ks < 2; ++ks)
          kf[kj][ks] = __builtin_bit_cast(bf16x8,
              *reinterpret_cast<const u16x8*>(
                  kcur + (kj * 16 + l16) * 64 + (((ks * 4 + g) ^ (l16 & 7)) * 8)));

      f32x4 s2[4][2];
#pragma unroll
      for (int kj = 0; kj < 4; ++kj)
#pragma unroll
        for (int qi = 0; qi < 2; ++qi) s2[kj][qi] = (f32x4){0.f, 0.f, 0.f, 0.f};
      __builtin_amdgcn_s_setprio(1);
#pragma unroll
      for (int ks = 0; ks < 2; ++ks)
#pragma unroll
        for (int kj = 0; kj < 4; ++kj)
#pragma unroll
          for (int qi = 0; qi < 2; ++qi)
            s2[kj][qi] = __builtin_amdgcn_mfma_f32_16x16x32_bf16(
                kf[kj][ks], qf[qi][ks], s2[kj][qi], 0, 0, 0);
      __builtin_amdgcn_s_setprio(0);

      if (kt == ntw - 1) {
#pragma unroll
        for (int kj = 0; kj < 4; ++kj)
#pragma unroll
          for (int qi = 0; qi < 2; ++qi) {
            u16x4 pv;
#pragma unroll
            for (int r = 0; r < 4; ++r) {
              float v = fmaxf(s2[kj][qi][r], 0.f);
              if (kj * 16 + g * 4 + r > qoff + qi * 16 + l16) v = 0.f;
              pv[r] = f2bf(v);
            }
            *reinterpret_cast<u16x4*>(pw + (qi * 16 + l16) * 72 + kj * 16 + g * 4) = pv;
          }
      } else {
#pragma unroll
        for (int kj = 0; kj < 4; ++kj)
#pragma unroll
          for (int qi = 0; qi < 2; ++qi) {
            u16x4 pv;
#pragma unroll
            for (int r = 0; r < 4; ++r) pv[r] = f2bf(fmaxf(s2[kj][qi][r], 0.f));
            *reinterpret_cast<u16x4*>(pw + (qi * 16 + l16) * 72 + kj * 16 + g * 4) = pv;
          }
      }

      bf16x8 vf[4][2];
#pragma unroll
      for (int ni = 0; ni < 4; ++ni)
#pragma unroll
        for (int kc = 0; kc < 2; ++kc)
          vf[ni][kc] = __builtin_bit_cast(bf16x8,
              *reinterpret_cast<const u16x8*>(
                  vcur + (ni * 16 + l16) * 64 + (((kc * 4 + g) ^ (l16 & 7)) * 8)));

      bf16x8 pa[2][2];
#pragma unroll
      for (int mi = 0; mi < 2; ++mi)
#pragma unroll
        for (int kc = 0; kc < 2; ++kc)
          pa[mi][kc] = __builtin_bit_cast(bf16x8,
              *reinterpret_cast<const u16x8*>(pw + (mi * 16 + l16) * 72 + kc * 32 + g * 8));
      __builtin_amdgcn_s_setprio(1);
#pragma unroll
      for (int kc = 0; kc < 2; ++kc)
#pragma unroll
        for (int ni = 0; ni < 4; ++ni)
#pragma unroll
          for (int mi = 0; mi < 2; ++mi)
            y[mi][ni] = __builtin_amdgcn_mfma_f32_16x16x32_bf16(
                pa[mi][kc], vf[ni][kc], y[mi][ni], 0, 0, 0);
      __builtin_amdgcn_s_setprio(0);
    }

    WAIT0_BAR();   // vmcnt(0)+lgkmcnt(0): stage landed AND all LDS reads done
  }
#undef ASTAGE

  float* outp = out + (size_t)b * 1024 * 768 + (size_t)h * 64;
#pragma unroll
  for (int mi = 0; mi < 2; ++mi)
#pragma unroll
    for (int r = 0; r < 4; ++r) {
      int t = q0 + mi * 16 + g * 4 + r;
#pragma unroll
      for (int ni = 0; ni < 4; ++ni)
        outp[(size_t)t * 768 + ni * 16 + l16] = y[mi][ni][r];
    }
}

extern "C" void kernel_launch(void* const* d_in, const int* in_sizes, int n_in,
                              void* d_out, int out_size, void* d_ws, size_t ws_size,
                              hipStream_t stream) {
  const float* x    = (const float*)d_in[0];
  const float* W    = (const float*)d_in[1];
  const float* bias = (const float*)d_in[2];
  float* out = (float*)d_out;
  char* ws = (char*)d_ws;

  // ws layout (bytes): xb 12.58MB | WbT 3.54MB | qb 12.58MB | kb 12.58MB | vTb 12.58MB
  u16* xb  = (u16*)(ws);
  u16* WbT = (u16*)(ws + 12582912);
  u16* qb  = (u16*)(ws + 16121856);
  u16* kb  = (u16*)(ws + 28704768);
  u16* vTb = (u16*)(ws + 41287680);

  hipLaunchKernelGGL(cvt_all_kernel, dim3(4800), dim3(256), 0, stream, x, xb, W, WbT);
  hipLaunchKernelGGL(gemm_qkv_kernel, dim3(64, 18), dim3(256), 0, stream,
                     xb, WbT, bias, qb, kb, vTb);
  hipLaunchKernelGGL(attn_kernel, dim3(96, 8), dim3(256), 0, stream, qb, kb, vTb, out);
}

// Round 19
// 77.382 us; speedup vs baseline: 1.0660x; 1.0660x over previous
//
#include <hip/hip_runtime.h>
#include <hip/hip_bf16.h>

typedef unsigned short u16;
typedef u16 u16x4 __attribute__((ext_vector_type(4)));
typedef u16 u16x8 __attribute__((ext_vector_type(8)));
typedef __bf16 bf16x8 __attribute__((ext_vector_type(8)));
typedef float f32x4 __attribute__((ext_vector_type(4)));

static __device__ __forceinline__ u16 f2bf(float f) {
  return __builtin_bit_cast(u16, __float2bfloat16(f));   // RTNE; pairs into v_cvt_pk_bf16_f32
}

// async global->LDS, 16B per lane. LDS dest = wave-uniform base + lane*16.
static __device__ __forceinline__ void gload16(const u16* g, u16* l) {
  __builtin_amdgcn_global_load_lds(
      (const __attribute__((address_space(1))) unsigned*)g,
      (__attribute__((address_space(3))) unsigned*)l, 16, 0, 0);
}

// Barriers guarding LDS buffer handoff MUST drain lgkmcnt inside the asm
// (rule #18: hipcc can sink register-only MFMAs below an asm s_barrier,
// leaving their feeding ds_reads outstanding across the barrier).
#define WAIT8_BAR() asm volatile("s_waitcnt vmcnt(8) lgkmcnt(0)\ns_barrier" ::: "memory")
#define WAIT0_BAR() asm volatile("s_waitcnt vmcnt(0) lgkmcnt(0)\ns_barrier" ::: "memory")
#define BAR()       asm volatile("s_waitcnt lgkmcnt(0)\ns_barrier" ::: "memory")

// ---------------- fused cvt: x f32->bf16 (blocks 0..3071) ----------------
//                  W [768][2304] f32 -> WbT [2304][768] bf16 (blocks 3072..4799)
__global__ __launch_bounds__(256) void cvt_all_kernel(const float* __restrict__ xin,
                                                      u16* __restrict__ xout,
                                                      const float* __restrict__ W,
                                                      u16* __restrict__ WT) {
  int bid = blockIdx.x;
  if (bid < 3072) {
    int i = bid * 256 + threadIdx.x;               // 8 elems per thread
    const float4* p = reinterpret_cast<const float4*>(xin) + (size_t)i * 2;
    float4 a = p[0], b = p[1];
    u16x8 o;
    o[0] = f2bf(a.x); o[1] = f2bf(a.y); o[2] = f2bf(a.z); o[3] = f2bf(a.w);
    o[4] = f2bf(b.x); o[5] = f2bf(b.y); o[6] = f2bf(b.z); o[7] = f2bf(b.w);
    reinterpret_cast<u16x8*>(xout)[i] = o;
  } else {
    int id = bid - 3072;                           // 0..1727
    int n  = (id % 9) * 256 + threadIdx.x;         // 0..2303
    int k0 = (id / 9) * 4;                         // 0..764
    u16x4 o;
#pragma unroll
    for (int j = 0; j < 4; ++j) o[j] = f2bf(W[(size_t)(k0 + j) * 2304 + n]);
    *reinterpret_cast<u16x4*>(WT + (size_t)n * 768 + k0) = o;
  }
}

// ---------------- QKV GEMM: [8192x768] @ [768x2304] + bias ----------------
// r15/r17-proven best structure: 128x128 tile, BK=64, both-sides XOR swizzle,
// 2-deep counted vmcnt(8) pipeline (12 phases, 32 MFMA/phase), 2 blocks/CU.
// Identity block map (m%8==XCD: measured-best L2, FETCH ~30MB).
// LDS-transpose epilogue (stride 72 -> 16B-aligned readback), coalesced q/k.
// q pre-scaled by 0.125. writes q[bh][t][d], k[bh][t][d], vT[bh][d][t].
// Family bracket (all measured): r14 BK=32 4-deep regressed; r16 256x128
// @1/CU regressed; r18 3-buffer @1/CU regressed. This is the 2-phase-family
// optimum (633 TF ~= documented structural ceiling m230/m233).

static __device__ __forceinline__ void gemm_compute64(
    const u16* __restrict__ as, const u16* __restrict__ bs,
    int wm, int wn, int l16, int g, f32x4 (&acc)[4][4]) {
  bf16x8 af[4][2], bfr[4][2];
#pragma unroll
  for (int mi = 0; mi < 4; ++mi)
#pragma unroll
    for (int ks = 0; ks < 2; ++ks)
      af[mi][ks] = __builtin_bit_cast(bf16x8,
          *reinterpret_cast<const u16x8*>(
              as + (wm + mi * 16 + l16) * 64 + (((ks * 4 + g) ^ (l16 & 7)) * 8)));
#pragma unroll
  for (int ni = 0; ni < 4; ++ni)
#pragma unroll
    for (int ks = 0; ks < 2; ++ks)
      bfr[ni][ks] = __builtin_bit_cast(bf16x8,
          *reinterpret_cast<const u16x8*>(
              bs + (wn + ni * 16 + l16) * 64 + (((ks * 4 + g) ^ (l16 & 7)) * 8)));
#pragma unroll
  for (int ks = 0; ks < 2; ++ks)
#pragma unroll
    for (int mi = 0; mi < 4; ++mi)
#pragma unroll
      for (int ni = 0; ni < 4; ++ni)
        acc[mi][ni] = __builtin_amdgcn_mfma_f32_16x16x32_bf16(
            af[mi][ks], bfr[ni][ks], acc[mi][ni], 0, 0, 0);
}

__global__ __launch_bounds__(256, 2) void gemm_qkv_kernel(
    const u16* __restrict__ A, const u16* __restrict__ Bt,
    const float* __restrict__ bias,
    u16* __restrict__ qb, u16* __restrict__ kb, u16* __restrict__ vTb) {
  __shared__ __align__(16) u16 smem[4 * 128 * 64];   // 64 KB: as0|as1|bs0|bs1
  u16* as0 = smem;
  u16* as1 = smem + 128 * 64;
  u16* bs0 = smem + 2 * 128 * 64;
  u16* bs1 = smem + 3 * 128 * 64;
  const int K = 768;
  int tid = threadIdx.x;
  int lane = tid & 63;
  int wave = tid >> 6;

  int m0 = blockIdx.x * 128;       // gridDim.x = 64 (identity map: m%8==XCD)
  int n0 = blockIdx.y * 128;       // gridDim.y = 18

  int wm = (wave >> 1) * 64;
  int wn = (wave & 1) * 64;
  int l16 = lane & 15, g = lane >> 4;

  int r8 = lane >> 3;
  int cs = (lane & 7) ^ (r8 & 7);
  const u16* gA = A  + (size_t)(m0 + wave * 32 + r8) * K + cs * 8;
  const u16* gB = Bt + (size_t)(n0 + wave * 32 + r8) * K + cs * 8;
  int lofs = wave * 2048;

  f32x4 acc[4][4];
#pragma unroll
  for (int mi = 0; mi < 4; ++mi)
#pragma unroll
    for (int ni = 0; ni < 4; ++ni) acc[mi][ni] = (f32x4){0.f, 0.f, 0.f, 0.f};

#define STAGE(Abuf, Bbuf, kk)                              \
  do {                                                     \
    gload16(gA + (kk),           Abuf + lofs);             \
    gload16(gA + (kk) +  8 * K,  Abuf + lofs + 512);       \
    gload16(gA + (kk) + 16 * K,  Abuf + lofs + 1024);      \
    gload16(gA + (kk) + 24 * K,  Abuf + lofs + 1536);      \
    gload16(gB + (kk),           Bbuf + lofs);             \
    gload16(gB + (kk) +  8 * K,  Bbuf + lofs + 512);       \
    gload16(gB + (kk) + 16 * K,  Bbuf + lofs + 1024);      \
    gload16(gB + (kk) + 24 * K,  Bbuf + lofs + 1536);      \
  } while (0)

  STAGE(as0, bs0, 0);
  STAGE(as1, bs1, 64);
  for (int j = 0; j < 5; ++j) {
    int k0 = j * 128;
    WAIT8_BAR();
    gemm_compute64(as0, bs0, wm, wn, l16, g, acc);
    BAR();
    STAGE(as0, bs0, k0 + 128);
    WAIT8_BAR();
    gemm_compute64(as1, bs1, wm, wn, l16, g, acc);
    BAR();
    STAGE(as1, bs1, k0 + 192);
  }
  WAIT8_BAR();
  gemm_compute64(as0, bs0, wm, wn, l16, g, acc);
  WAIT0_BAR();
  gemm_compute64(as1, bs1, wm, wn, l16, g, acc);
#undef STAGE

  BAR();   // all LDS reads drained -> smem reusable as epilogue scratch

  // epilogue. wave tile = 64 t-rows x 64 n-cols, one region & one head each.
  int tbase = m0 & 1023;
  int b = m0 >> 10;
  int nbase = n0 + wn;
  int region = nbase / 768;
  int c0 = nbase - region * 768;
  int h = c0 >> 6;
  int bh = b * 12 + h;
  int tb0 = tbase + wm;
  float scl = (region == 0) ? 0.125f : 1.0f;
  float bvs[4];
#pragma unroll
  for (int ni = 0; ni < 4; ++ni) bvs[ni] = bias[nbase + ni * 16 + l16] * scl;

  if (region == 2) {
    // vT[bh][d][t]: b64 stores along t
    int d0 = c0 & 63;
    int g4 = g * 4;
#pragma unroll
    for (int ni = 0; ni < 4; ++ni) {
      int d = d0 + ni * 16 + l16;
#pragma unroll
      for (int mi = 0; mi < 4; ++mi) {
        int t0 = tb0 + mi * 16 + g4;
        u16x4 pv;
#pragma unroll
        for (int r = 0; r < 4; ++r) pv[r] = f2bf(acc[mi][ni][r] + bvs[ni]);
        *reinterpret_cast<u16x4*>(vTb + ((size_t)bh * 64 + d) * 1024 + t0) = pv;
      }
    }
  } else {
    // q/k[bh][t][d]: transpose via per-wave LDS scratch (stride 72 -> 144B
    // rows, 16B-aligned readback), then 8 coalesced dwordx4 stores.
    u16* scr = smem + wave * (64 * 72);
    u16* dst = (region == 0) ? qb : kb;
#pragma unroll
    for (int ni = 0; ni < 4; ++ni)
#pragma unroll
      for (int mi = 0; mi < 4; ++mi)
#pragma unroll
        for (int r = 0; r < 4; ++r)
          scr[(mi * 16 + g * 4 + r) * 72 + ni * 16 + l16] =
              f2bf(fmaf(acc[mi][ni][r], scl, bvs[ni]));
    int rr = lane >> 3, cc = lane & 7;
#pragma unroll
    for (int i = 0; i < 8; ++i) {
      u16x8 v = *reinterpret_cast<const u16x8*>(scr + (i * 8 + rr) * 72 + cc * 8);
      *reinterpret_cast<u16x8*>(
          dst + ((size_t)bh * 1024 + tb0 + i * 8 + rr) * 64 + cc * 8) = v;
    }
  }
}

// ---------------- causal relu attention (block-shared K/V staging) ----------------
// y[b,h,q,:] = sum_{k<=q} relu(q.k) * v[k]   (scale pre-folded into q)
// Block = 4 waves, same head, q-groups qbase+{0,32,64,96}. K/V 64-key tiles
// staged once per block into double-buffered LDS via global_load_lds, XOR-chunk
// swizzle (both-sides). One vmcnt(0)+lgkmcnt(0)+barrier per tile.
__global__ __launch_bounds__(256, 3) void attn_kernel(
    const u16* __restrict__ qb, const u16* __restrict__ kb,
    const u16* __restrict__ vTb, float* __restrict__ out) {
  __shared__ __align__(16) u16 kbuf0[64 * 64], kbuf1[64 * 64];
  __shared__ __align__(16) u16 vbuf0[64 * 64], vbuf1[64 * 64];
  __shared__ __align__(16) u16 plds[4][32 * 72];
  int lane = threadIdx.x & 63;
  int wave = threadIdx.x >> 6;
  int bh = blockIdx.x;                           // 0..95
  int qbase = (7 - blockIdx.y) * 128;            // heaviest blocks first
  int q0 = qbase + wave * 32;
  int b = bh / 12, h = bh - b * 12;
  const u16* Q  = qb  + (size_t)bh * 65536;
  const u16* Kp = kb  + (size_t)bh * 65536;
  const u16* Vt = vTb + (size_t)bh * 65536;
  int l16 = lane & 15, g = lane >> 4;
  u16* pw = &plds[wave][0];

  int ntw = (q0 >> 6) + 1;        // this wave's active tiles
  int ntB = (qbase >> 6) + 2;     // block-uniform loop bound
  int qoff = q0 & 63;             // 0 or 32

  int r8q = lane >> 3;
  int csw = (lane & 7) ^ (r8q & 7);
  const u16* kSrc = Kp + (size_t)(wave * 16 + r8q) * 64 + csw * 8;
  const u16* vSrc = Vt + (size_t)(wave * 16 + r8q) * 1024 + csw * 8;
  int sofs = wave * 1024;

#define ASTAGE(kbuf, vbuf, kbase)                                   \
  do {                                                              \
    gload16(kSrc + (size_t)(kbase) * 64,       kbuf + sofs);        \
    gload16(kSrc + (size_t)((kbase) + 8) * 64, kbuf + sofs + 512);  \
    gload16(vSrc + (kbase),                    vbuf + sofs);        \
    gload16(vSrc + (kbase) + 8 * 1024,         vbuf + sofs + 512);  \
  } while (0)

  bf16x8 qf[2][2];
#pragma unroll
  for (int qi = 0; qi < 2; ++qi)
#pragma unroll
    for (int ks = 0; ks < 2; ++ks)
      qf[qi][ks] = __builtin_bit_cast(bf16x8,
          *reinterpret_cast<const u16x8*>(Q + (q0 + qi * 16 + l16) * 64 + ks * 32 + g * 8));

  f32x4 y[2][4];
#pragma unroll
  for (int mi = 0; mi < 2; ++mi)
#pragma unroll
    for (int ni = 0; ni < 4; ++ni) y[mi][ni] = (f32x4){0.f, 0.f, 0.f, 0.f};

  ASTAGE(kbuf0, vbuf0, 0);
  WAIT0_BAR();

  for (int kt = 0; kt < ntB; ++kt) {
    u16 *kcur, *vcur, *knx, *vnx;
    if (kt & 1) { kcur = kbuf1; vcur = vbuf1; knx = kbuf0; vnx = vbuf0; }
    else        { kcur = kbuf0; vcur = vbuf0; knx = kbuf1; vnx = vbuf1; }

    if (kt + 1 < ntB) ASTAGE(knx, vnx, (kt + 1) << 6);

    if (kt < ntw) {
      bf16x8 kf[4][2];
#pragma unroll
      for (int kj = 0; kj < 4; ++kj)
#pragma unroll
        for (int ks = 0; ks < 2; ++ks)
          kf[kj][ks] = __builtin_bit_cast(bf16x8,
              *reinterpret_cast<const u16x8*>(
                  kcur + (kj * 16 + l16) * 64 + (((ks * 4 + g) ^ (l16 & 7)) * 8)));

      f32x4 s2[4][2];
#pragma unroll
      for (int kj = 0; kj < 4; ++kj)
#pragma unroll
        for (int qi = 0; qi < 2; ++qi) s2[kj][qi] = (f32x4){0.f, 0.f, 0.f, 0.f};
      __builtin_amdgcn_s_setprio(1);
#pragma unroll
      for (int ks = 0; ks < 2; ++ks)
#pragma unroll
        for (int kj = 0; kj < 4; ++kj)
#pragma unroll
          for (int qi = 0; qi < 2; ++qi)
            s2[kj][qi] = __builtin_amdgcn_mfma_f32_16x16x32_bf16(
                kf[kj][ks], qf[qi][ks], s2[kj][qi], 0, 0, 0);
      __builtin_amdgcn_s_setprio(0);

      if (kt == ntw - 1) {
#pragma unroll
        for (int kj = 0; kj < 4; ++kj)
#pragma unroll
          for (int qi = 0; qi < 2; ++qi) {
            u16x4 pv;
#pragma unroll
            for (int r = 0; r < 4; ++r) {
              float v = fmaxf(s2[kj][qi][r], 0.f);
              if (kj * 16 + g * 4 + r > qoff + qi * 16 + l16) v = 0.f;
              pv[r] = f2bf(v);
            }
            *reinterpret_cast<u16x4*>(pw + (qi * 16 + l16) * 72 + kj * 16 + g * 4) = pv;
          }
      } else {
#pragma unroll
        for (int kj = 0; kj < 4; ++kj)
#pragma unroll
          for (int qi = 0; qi < 2; ++qi) {
            u16x4 pv;
#pragma unroll
            for (int r = 0; r < 4; ++r) pv[r] = f2bf(fmaxf(s2[kj][qi][r], 0.f));
            *reinterpret_cast<u16x4*>(pw + (qi * 16 + l16) * 72 + kj * 16 + g * 4) = pv;
          }
      }

      bf16x8 vf[4][2];
#pragma unroll
      for (int ni = 0; ni < 4; ++ni)
#pragma unroll
        for (int kc = 0; kc < 2; ++kc)
          vf[ni][kc] = __builtin_bit_cast(bf16x8,
              *reinterpret_cast<const u16x8*>(
                  vcur + (ni * 16 + l16) * 64 + (((kc * 4 + g) ^ (l16 & 7)) * 8)));

      bf16x8 pa[2][2];
#pragma unroll
      for (int mi = 0; mi < 2; ++mi)
#pragma unroll
        for (int kc = 0; kc < 2; ++kc)
          pa[mi][kc] = __builtin_bit_cast(bf16x8,
              *reinterpret_cast<const u16x8*>(pw + (mi * 16 + l16) * 72 + kc * 32 + g * 8));
      __builtin_amdgcn_s_setprio(1);
#pragma unroll
      for (int kc = 0; kc < 2; ++kc)
#pragma unroll
        for (int ni = 0; ni < 4; ++ni)
#pragma unroll
          for (int mi = 0; mi < 2; ++mi)
            y[mi][ni] = __builtin_amdgcn_mfma_f32_16x16x32_bf16(
                pa[mi][kc], vf[ni][kc], y[mi][ni], 0, 0, 0);
      __builtin_amdgcn_s_setprio(0);
    }

    WAIT0_BAR();   // vmcnt(0)+lgkmcnt(0): stage landed AND all LDS reads done
  }
#undef ASTAGE

  float* outp = out + (size_t)b * 1024 * 768 + (size_t)h * 64;
#pragma unroll
  for (int mi = 0; mi < 2; ++mi)
#pragma unroll
    for (int r = 0; r < 4; ++r) {
      int t = q0 + mi * 16 + g * 4 + r;
#pragma unroll
      for (int ni = 0; ni < 4; ++ni)
        outp[(size_t)t * 768 + ni * 16 + l16] = y[mi][ni][r];
    }
}

extern "C" void kernel_launch(void* const* d_in, const int* in_sizes, int n_in,
                              void* d_out, int out_size, void* d_ws, size_t ws_size,
                              hipStream_t stream) {
  const float* x    = (const float*)d_in[0];
  const float* W    = (const float*)d_in[1];
  const float* bias = (const float*)d_in[2];
  float* out = (float*)d_out;
  char* ws = (char*)d_ws;

  // ws layout (bytes): xb 12.58MB | WbT 3.54MB | qb 12.58MB | kb 12.58MB | vTb 12.58MB
  u16* xb  = (u16*)(ws);
  u16* WbT = (u16*)(ws + 12582912);
  u16* qb  = (u16*)(ws + 16121856);
  u16* kb  = (u16*)(ws + 28704768);
  u16* vTb = (u16*)(ws + 41287680);

  hipLaunchKernelGGL(cvt_all_kernel, dim3(4800), dim3(256), 0, stream, x, xb, W, WbT);
  hipLaunchKernelGGL(gemm_qkv_kernel, dim3(64, 18), dim3(256), 0, stream,
                     xb, WbT, bias, qb, kb, vTb);
  hipLaunchKernelGGL(attn_kernel, dim3(96, 8), dim3(256), 0, stream, qb, kb, vTb, out);
}